// Round 16
// baseline (32.361 us; speedup 1.0000x reference)
//
#include <hip/hip_runtime.h>
#include <hip/hip_bf16.h>
#include <math.h>

#define L_SEQ 1024
#define DIMSZ 512
#define NH 8
#define ND 64
#define NB 2
#define CHUNK 64
#define NC (L_SEQ / CHUNK)   // 16
#define BHTOT (NB * NH)      // 16
#define MTOT 2048
#define KEFF 512
#define BM 64
#define BN 128

// XOR swizzle for 2B-element LDS tiles (row stride 64 elems = 128B):
// spreads 8 consecutive rows across 8 distinct 16B slots -> conflict-free
// ds_read_b128 fragments (G4).  col must stay multiple of 8 for b128 (ok:
// (row&7)<<3 is a multiple of 8).
#define SWZ(row, col) ((col) ^ (((row) & 7) << 3))

typedef __attribute__((ext_vector_type(8))) _Float16 f16x8;
typedef __attribute__((ext_vector_type(4))) float f32x4;

#define GLD16(g, l) __builtin_amdgcn_global_load_lds( \
    (const __attribute__((address_space(1))) unsigned int*)(g), \
    (__attribute__((address_space(3))) unsigned int*)(l), 16, 0, 0)

__device__ static inline unsigned short f2h(float f) {
    union { _Float16 h; unsigned short u; } x;
    x.h = (_Float16)f;
    return x.u;
}
__device__ static inline float h2f(unsigned short u) {
    union { unsigned short u; _Float16 h; } x;
    x.u = u;
    return (float)x.h;
}
__device__ static inline unsigned packh2(float a, float b) {
    return (unsigned)f2h(a) | ((unsigned)f2h(b) << 16);
}

// ---------------------------------------------------------------------------
// pack: [0,1024)    A[n][k] = fp16(x)                    (2048 x 512)
//       [1024,1792) B~ rows: q -> o ; k/v -> 512+(o>>6)*128+(which-1)*64+(o&63)
//       [1792,1800) lcT[h][e*64+d] = packh2(lc[h][d][e])
// ---------------------------------------------------------------------------
__global__ __launch_bounds__(256) void pack_kernel(
    const float* __restrict__ x,
    const float* __restrict__ wq, const float* __restrict__ wk, const float* __restrict__ wv,
    const float* __restrict__ lc_re, const float* __restrict__ lc_im,
    unsigned short* __restrict__ A, unsigned short* __restrict__ Bm,
    unsigned* __restrict__ lcT)
{
    __shared__ unsigned T[64][65];
    const int bid = blockIdx.x;
    const int tid = threadIdx.x;
    if (bid < 1024) {
        const int i = bid * 256 + tid;
        const int n  = i >> 7;
        const int kq = (i & 127) << 2;
        const float4 xv = *(const float4*)(x + (size_t)n * DIMSZ + kq);
        *(ushort4*)(A + (size_t)n * KEFF + kq) =
            make_ushort4(f2h(xv.x), f2h(xv.y), f2h(xv.z), f2h(xv.w));
    } else if (bid < 1792) {
        const int idx = bid - 1024;
        const int which = idx >> 8;
        const float* w = which == 0 ? wq : (which == 1 ? wk : wv);
        const int i = (idx & 255) * 256 + tid;
        const int o  = i >> 7;
        const int kq = (i & 127) << 2;
        const float4 wv4 = *(const float4*)(w + (size_t)o * DIMSZ + kq);
        const int row = (which == 0) ? o
                      : 512 + (which - 1) * 64 + (o >> 6) * 128 + (o & 63);
        *(ushort4*)(Bm + (size_t)row * KEFF + kq) =
            make_ushort4(f2h(wv4.x), f2h(wv4.y), f2h(wv4.z), f2h(wv4.w));
    } else {
        const int h = bid - 1792;
        const int e = tid & 63;
        #pragma unroll
        for (int i = 0; i < 16; ++i) {
            const int d = i*4 + (tid >> 6);
            T[e][d] = packh2(lc_re[h*4096 + d*64 + e], lc_im[h*4096 + d*64 + e]);
        }
        __syncthreads();
        const int d = tid & 63;
        #pragma unroll
        for (int i = 0; i < 16; ++i) {
            const int e2 = i*4 + (tid >> 6);
            lcT[h*4096 + e2*64 + d] = T[e2][d];
        }
    }
}

// ---------------------------------------------------------------------------
// gemm_kv: 384 blocks, kv-heavy blocks dispatched FIRST (q-panels last so
// the scheduling tail is the light blocks).  sw<128: q-block.  sw>=128:
// [k|v]-block + fused chunk_kv (swizzled LDS overlay, incremental
// rotation/decay, MFMA KV^T -> packed-fp16 kvB).
// ---------------------------------------------------------------------------
__global__ __launch_bounds__(256) void gemm_kv_kernel(
    const unsigned short* __restrict__ A, const unsigned short* __restrict__ Bm,
    const float* __restrict__ bq, const float* __restrict__ bk, const float* __restrict__ bv,
    const float* __restrict__ ph_re, const float* __restrict__ ph_im,
    const float* __restrict__ ampl,
    unsigned short* __restrict__ qo, unsigned short* __restrict__ ko,
    unsigned short* __restrict__ vo, unsigned* __restrict__ kvB)
{
    __shared__ __align__(16) char lds[49152];   // gemm: 2 x [A 8KB | B 16KB]
    const int tid  = threadIdx.x;
    const int lane = tid & 63;
    const int wave = tid >> 6;

    // kv-first scheduling: bid0 < 256 -> kv blocks (XCD-spread), else q.
    const int bid0 = blockIdx.x;
    int sw;
    if (bid0 < 256) sw = 128 + ((bid0 & 7) * 32 + (bid0 >> 3));
    else            { const int r = bid0 - 256; sw = (r & 7) * 16 + (r >> 3); }
    const bool isQ = sw < 128;
    int mtile, brow0, h = 0, panel = 0;
    if (isQ) { panel = sw & 3; mtile = sw >> 2; brow0 = panel * 128; }
    else     { const int r = sw - 128; h = r & 7; mtile = r >> 3; brow0 = 512 + h * 128; }
    const int row0 = mtile * 64;
    const int wr = wave >> 1, wc = wave & 1;     // wave tile 32 x 64

    const int srow = tid >> 3;
    const int sin  = (tid & 7) << 4;
    size_t goffA[2], goffB[4];
    #pragma unroll
    for (int c = 0; c < 2; ++c) {
        const int row = c * 32 + srow;
        const int swz = sin ^ ((row & 7) << 4);
        goffA[c] = (size_t)(row0 + row) * (KEFF * 2) + swz;
    }
    #pragma unroll
    for (int c = 0; c < 4; ++c) {
        const int row = c * 32 + srow;
        const int swz = sin ^ ((row & 7) << 4);
        goffB[c] = (size_t)(brow0 + row) * (KEFF * 2) + swz;
    }
    const int ldst = tid * 16;
    const char* Abyte = (const char*)A;
    const char* Bbyte = (const char*)Bm;

    f32x4 acc[2][4];
    const f32x4 zf = {0.f, 0.f, 0.f, 0.f};
    #pragma unroll
    for (int m = 0; m < 2; ++m)
        #pragma unroll
        for (int n = 0; n < 4; ++n) acc[m][n] = zf;

    auto stage = [&](int buf, int t) {
        char* la = lds + buf * 24576;
        char* lb = la + 8192;
        const size_t kb = (size_t)t * 128;
        #pragma unroll
        for (int c = 0; c < 2; ++c)
            GLD16(Abyte + goffA[c] + kb, la + c * 4096 + ldst);
        #pragma unroll
        for (int c = 0; c < 4; ++c)
            GLD16(Bbyte + goffB[c] + kb, lb + c * 4096 + ldst);
    };

    const int rl = lane & 15;
    const int kg = lane >> 4;
    const int rswz = (rl & 7) << 4;

    auto compute = [&](int buf) {
        const char* la = lds + buf * 24576;
        const char* lb = la + 8192;
        #pragma unroll
        for (int ks = 0; ks < 2; ++ks) {
            f16x8 av[2], bvv[4];
            #pragma unroll
            for (int m = 0; m < 2; ++m) {
                const int row = wr * 32 + m * 16 + rl;
                const int addr = (row * 128 + ks * 64 + kg * 16) ^ rswz;
                av[m] = *(const f16x8*)(la + addr);
            }
            #pragma unroll
            for (int n = 0; n < 4; ++n) {
                const int row = wc * 64 + n * 16 + rl;
                const int addr = (row * 128 + ks * 64 + kg * 16) ^ rswz;
                bvv[n] = *(const f16x8*)(lb + addr);
            }
            #pragma unroll
            for (int m = 0; m < 2; ++m)
                #pragma unroll
                for (int n = 0; n < 4; ++n)
                    acc[m][n] = __builtin_amdgcn_mfma_f32_16x16x32_f16(
                        av[m], bvv[n], acc[m][n], 0, 0, 0);
        }
    };

    stage(0, 0);
    __syncthreads();
    const int NT = KEFF / 64;   // 8
    for (int t = 0; t < NT; ++t) {
        if (t + 1 < NT) stage((t + 1) & 1, t + 1);
        compute(t & 1);
        __syncthreads();
    }
    // all GEMM LDS dead from here on

    if (isQ) {
        #pragma unroll
        for (int n = 0; n < 4; ++n) {
            const int cabs = panel * 128 + wc * 64 + n * 16 + rl;
            const float bs = bq[cabs];
            #pragma unroll
            for (int m = 0; m < 2; ++m) {
                const int rb = row0 + wr * 32 + m * 16 + kg * 4;
                #pragma unroll
                for (int r = 0; r < 4; ++r)
                    qo[(size_t)(rb + r) * DIMSZ + cabs] = f2h(acc[m][n][r] + bs);
            }
        }
        return;
    }

    // ---- kv-block epilogue: global store + swizzled LDS stage (overlay) ----
    _Float16 (*KTR)[64] = (_Float16(*)[64])(lds);            // 8192 B
    _Float16 (*KTI)[64] = (_Float16(*)[64])(lds + 8192);     // 8192 B
    _Float16 (*VWT)[64] = (_Float16(*)[64])(lds + 16384);    // 8192 B

    unsigned short* outp = wc == 0 ? ko : vo;
    _Float16 (*RAW)[64] = wc == 0 ? KTR : VWT;   // raw k -> KTR, raw v -> VWT
    #pragma unroll
    for (int n = 0; n < 4; ++n) {
        const int cl = h * 64 + n * 16 + rl;
        const int drow = n * 16 + rl;
        const float bs = (wc == 0 ? bk : bv)[cl];
        #pragma unroll
        for (int m = 0; m < 2; ++m) {
            const int jb = wr * 32 + m * 16 + kg * 4;
            #pragma unroll
            for (int r = 0; r < 4; ++r) {
                const float val = acc[m][n][r] + bs;
                outp[(size_t)(row0 + jb + r) * DIMSZ + cl] = f2h(val);
                RAW[drow][SWZ(drow, jb + r)] = (_Float16)val;
            }
        }
    }
    __syncthreads();

    // ---- rotate/decay (incremental: j descending -> p ascending) ----
    const float amp = 1.0f / (1.0f + expf(-ampl[h]));
    const float la_ = logf(amp);
    const float th = atan2f(ph_im[h*ND + lane], ph_re[h*ND + lane]);
    float sth2, cth2; sincosf(th, &sth2, &cth2);
    const float p0 = (float)(CHUNK - 1 - (wave*16 + 15));
    float ap = expf(la_ * p0);
    float sp, cp; sincosf(th * p0, &sp, &cp);
    #pragma unroll
    for (int jj = 15; jj >= 0; --jj) {
        const int j = wave*16 + jj;
        const int cj = SWZ(lane, j);
        const float kk = (float)KTR[lane][cj];
        const float vv = (float)VWT[lane][cj];
        KTR[lane][cj] = (_Float16)(kk * cp);
        KTI[lane][cj] = (_Float16)(kk * sp);
        VWT[lane][cj] = (_Float16)(vv * ap);
        const float ncp = cp*cth2 - sp*sth2;          // p += 1
        sp = cp*sth2 + sp*cth2; cp = ncp;
        ap *= amp;
    }
    __syncthreads();

    // ---- KV^T MFMA + packed kvB store ----
    const int b = mtile >> 4, c = mtile & 15;
    unsigned* dst = kvB + (size_t)(((b * NH + h) << 4) | c) * (ND * ND);
    #pragma unroll
    for (int i = 0; i < 4; ++i) {
        const int mt = wave, nt = i;         // e-tile = wave, d-tile = i
        f32x4 aR = zf, aI = zf;
        const int mrow = mt*16 + rl, nrow = nt*16 + rl;
        #pragma unroll
        for (int ks = 0; ks < 2; ++ks) {
            const f16x8 av = *(const f16x8*)&VWT[mrow][SWZ(mrow, ks*32 + kg*8)];
            const f16x8 br = *(const f16x8*)&KTR[nrow][SWZ(nrow, ks*32 + kg*8)];
            const f16x8 bi = *(const f16x8*)&KTI[nrow][SWZ(nrow, ks*32 + kg*8)];
            aR = __builtin_amdgcn_mfma_f32_16x16x32_f16(av, br, aR, 0, 0, 0);
            aI = __builtin_amdgcn_mfma_f32_16x16x32_f16(av, bi, aI, 0, 0, 0);
        }
        const int d = nt*16 + rl;
        #pragma unroll
        for (int r = 0; r < 4; ++r) {
            const int e = mt*16 + kg*4 + r;
            dst[e*ND + d] = packh2(aR[r], aI[r]);
        }
    }
}

// ---------------------------------------------------------------------------
// scan (packed fp16, transposed layout, coalesced packed lcT): idx = e*64+d.
// ---------------------------------------------------------------------------
__global__ __launch_bounds__(256) void scan_kernel(
    unsigned* __restrict__ kvB, const unsigned* __restrict__ lcT,
    const float* __restrict__ ph_re, const float* __restrict__ ph_im,
    const float* __restrict__ ampl)
{
    const int gid = blockIdx.x * 256 + threadIdx.x;   // 65536
    const int bh = gid >> 12;
    const int idx = gid & 4095;
    const int h = bh & 7;
    const int d = idx & 63;

    const float th = atan2f(ph_im[h*ND + d], ph_re[h*ND + d]);
    const float la = -logf(1.0f + expf(-ampl[h]));
    const float ampC = expf(la * (float)CHUNK);
    float s, ct; sincosf(th * (float)CHUNK, &s, &ct);
    const float aCr = ampC * ct, aCi = ampC * s;

    unsigned* base = kvB + (size_t)bh * NC * (ND*ND) + idx;
    unsigned tl[NC];
    #pragma unroll
    for (int cc = 0; cc < NC; ++cc) tl[cc] = base[(size_t)cc * (ND*ND)];

    const unsigned lcp = lcT[h*4096 + idx];
    float Sr = h2f((unsigned short)(lcp & 0xffffu));
    float Si = h2f((unsigned short)(lcp >> 16));
    #pragma unroll
    for (int cc = 0; cc < NC; ++cc) {
        base[(size_t)cc * (ND*ND)] = packh2(Sr, Si);
        const float tr = h2f((unsigned short)(tl[cc] & 0xffffu));
        const float ti = h2f((unsigned short)(tl[cc] >> 16));
        const float nr = aCr*Sr - aCi*Si + tr;
        const float ni = aCr*Si + aCi*Sr + ti;
        Sr = nr; Si = ni;
    }
}

// ---------------------------------------------------------------------------
// chunk_out (MFMA): ONE 512-thread block per (b,h,c); 8 waves; 64 output
// rows.  All LDS tiles [64][64] with SWZ XOR layout (conflict-free b128
// fragments).  Fully-masked score tiles (rt<nt) skip their MFMAs.
// ---------------------------------------------------------------------------
__global__ __launch_bounds__(512) void chunk_out_kernel(
    const unsigned short* __restrict__ q, const unsigned short* __restrict__ k,
    const unsigned short* __restrict__ v, const unsigned* __restrict__ Bst,
    const float* __restrict__ ph_re, const float* __restrict__ ph_im,
    const float* __restrict__ ampl, float* __restrict__ out)
{
    __shared__ __align__(16) _Float16 QhR[64][64], QhI[64][64];
    __shared__ __align__(16) _Float16 KhR[64][64], KhI[64][64];   // -> B'R/-B'I
    __shared__ __align__(16) _Float16 VT[64][64];
    __shared__ __align__(16) _Float16 SA[64][64];
    __shared__ float apw[80];

    const int bhc = blockIdx.x;
    const int c  = bhc & (NC - 1);
    const int bh = bhc >> 4;
    const int b = bh >> 3, h = bh & 7;
    const int tid = threadIdx.x;
    const int lane = tid & 63, w = tid >> 6;
    const int rl = lane & 15, kg = lane >> 4;
    const int rt = w >> 1;                        // row-tile (0..3)

    const float la = -logf(1.0f + expf(-ampl[h]));
    if (tid < 72) apw[tid] = expf(la * (float)tid);
    const float th = atan2f(ph_im[h*ND + lane], ph_re[h*ND + lane]);
    float sth_, cth_; sincosf(th, &sth_, &cth_);

    // early B-state loads (8 per thread; idx = ii*512 + tid -> e = ii*8+w)
    unsigned breg[8];
    const unsigned* Bb = Bst + (size_t)bhc * (ND*ND);
    #pragma unroll
    for (int ii = 0; ii < 8; ++ii) breg[ii] = Bb[ii*512 + tid];

    // ---- Q + K/V staging (8 rows per wave, incremental rotation) ----
    {
        const int jbase = w * 8;
        float sr, cr; sincosf(th * (float)jbase, &sr, &cr);
        #pragma unroll
        for (int jj = 0; jj < 8; ++jj) {
            const int j = jbase + jj;
            const size_t off = ((size_t)(b*L_SEQ + c*CHUNK + j)) * DIMSZ + h*ND + lane;
            const float qq = h2f(q[off]);
            const float kk = h2f(k[off]);
            const int cl = SWZ(j, lane);
            QhR[j][cl] = (_Float16)(qq * cr);
            QhI[j][cl] = (_Float16)(qq * sr);
            KhR[j][cl] = (_Float16)(kk * cr);
            KhI[j][cl] = (_Float16)(kk * sr);
            VT[lane][SWZ(lane, j)] = (_Float16)h2f(v[off]);
            const float ncr = cr*cth_ - sr*sth_;
            sr = cr*sth_ + sr*cth_; cr = ncr;
        }
    }
    __syncthreads();

    // ---- scores (skip fully-masked tiles rt < nt) ----
    const f32x4 zf = {0.f, 0.f, 0.f, 0.f};
    f32x4 sacc[2] = {zf, zf};
    #pragma unroll
    for (int t = 0; t < 2; ++t) {
        const int nt = (w & 1)*2 + t;
        if (rt >= nt) {
            const int arow = rt*16 + rl, brow = nt*16 + rl;
            #pragma unroll
            for (int ks = 0; ks < 2; ++ks) {
                const f16x8 aR = *(const f16x8*)&QhR[arow][SWZ(arow, ks*32 + kg*8)];
                const f16x8 bR = *(const f16x8*)&KhR[brow][SWZ(brow, ks*32 + kg*8)];
                sacc[t] = __builtin_amdgcn_mfma_f32_16x16x32_f16(aR, bR, sacc[t], 0, 0, 0);
                const f16x8 aI = *(const f16x8*)&QhI[arow][SWZ(arow, ks*32 + kg*8)];
                const f16x8 bI = *(const f16x8*)&KhI[brow][SWZ(brow, ks*32 + kg*8)];
                sacc[t] = __builtin_amdgcn_mfma_f32_16x16x32_f16(aI, bI, sacc[t], 0, 0, 0);
            }
        }
    }
    __syncthreads();   // everyone done reading Kh

    // ---- SA = mask(scores) fp16;  B' = e^{i th_d} B -> Kh space ----
    #pragma unroll
    for (int t = 0; t < 2; ++t) {
        const int nt = (w & 1)*2 + t;
        #pragma unroll
        for (int r = 0; r < 4; ++r) {
            const int rowm = rt*16 + kg*4 + r;
            const int jp = nt*16 + rl;
            const int delta = rowm - jp;
            const float val = (delta >= 0) ? sacc[t][r] * apw[delta] : 0.0f;
            SA[rowm][SWZ(rowm, jp)] = (_Float16)val;
        }
    }
    #pragma unroll
    for (int ii = 0; ii < 8; ++ii) {
        const int e = ii*8 + w;     // idx = ii*512 + tid -> e = ii*8 + w, d = lane
        const float br = h2f((unsigned short)(breg[ii] & 0xffffu));
        const float bi = h2f((unsigned short)(breg[ii] >> 16));
        const int cl = SWZ(e, lane);
        KhR[e][cl] = (_Float16)(br*cth_ - bi*sth_);      //  B'R
        KhI[e][cl] = (_Float16)(-(br*sth_ + bi*cth_));   // -B'I
    }
    __syncthreads();

    // ---- PV + cross (cross uses Qh directly: Re(qhat . B')) ----
    #pragma unroll
    for (int t = 0; t < 2; ++t) {
        const int nt = (w & 1)*2 + t;
        f32x4 accO = zf, accC = zf;
        const int arow = rt*16 + rl, brow = nt*16 + rl;
        #pragma unroll
        for (int ks = 0; ks < 2; ++ks) {
            const f16x8 aS = *(const f16x8*)&SA[arow][SWZ(arow, ks*32 + kg*8)];
            const f16x8 bV = *(const f16x8*)&VT[brow][SWZ(brow, ks*32 + kg*8)];
            accO = __builtin_amdgcn_mfma_f32_16x16x32_f16(aS, bV, accO, 0, 0, 0);
            const f16x8 aR = *(const f16x8*)&QhR[arow][SWZ(arow, ks*32 + kg*8)];
            const f16x8 bBR = *(const f16x8*)&KhR[brow][SWZ(brow, ks*32 + kg*8)];
            accC = __builtin_amdgcn_mfma_f32_16x16x32_f16(aR, bBR, accC, 0, 0, 0);
            const f16x8 aI = *(const f16x8*)&QhI[arow][SWZ(arow, ks*32 + kg*8)];
            const f16x8 bBI = *(const f16x8*)&KhI[brow][SWZ(brow, ks*32 + kg*8)];
            accC = __builtin_amdgcn_mfma_f32_16x16x32_f16(aI, bBI, accC, 0, 0, 0);
        }
        const int e = nt*16 + rl;
        #pragma unroll
        for (int r = 0; r < 4; ++r) {
            const int rowm = rt*16 + kg*4 + r;
            const float cs = apw[rowm + 1];
            out[((size_t)(b*L_SEQ + c*CHUNK + rowm)) * DIMSZ + h*ND + e] =
                accO[r] + cs * accC[r];
        }
    }
}

// ---------------------------------------------------------------------------
extern "C" void kernel_launch(void* const* d_in, const int* in_sizes, int n_in,
                              void* d_out, int out_size, void* d_ws, size_t ws_size,
                              hipStream_t stream)
{
    const float* x     = (const float*)d_in[0];
    const float* wq_w  = (const float*)d_in[1];
    const float* wq_b  = (const float*)d_in[2];
    const float* wk_w  = (const float*)d_in[3];
    const float* wk_b  = (const float*)d_in[4];
    const float* wv_w  = (const float*)d_in[5];
    const float* wv_b  = (const float*)d_in[6];
    const float* ph_re = (const float*)d_in[7];
    const float* ph_im = (const float*)d_in[8];
    const float* ampl  = (const float*)d_in[9];
    const float* lc_re = (const float*)d_in[10];
    const float* lc_im = (const float*)d_in[11];
    float* out = (float*)d_out;

    char* wsb = (char*)d_ws;
    const size_t MB = 1024 * 1024;
    unsigned short* q = (unsigned short*)(wsb + 0);          // 2 MB (fp16)
    unsigned short* k = (unsigned short*)(wsb + 2 * MB);     // 2 MB
    unsigned short* v = (unsigned short*)(wsb + 4 * MB);     // 2 MB
    unsigned* kvB = (unsigned*)(wsb + 8 * MB);               // 4 MB (packed h2)
    unsigned short* Apk = (unsigned short*)(wsb + 13 * MB);  // 2 MB
    unsigned short* Bpk = (unsigned short*)(wsb + 16 * MB);  // 1.5 MB
    unsigned* lcT = (unsigned*)(wsb + 18 * MB);              // 128 KB

    pack_kernel<<<1800, 256, 0, stream>>>(
        x, wq_w, wk_w, wv_w, lc_re, lc_im, Apk, Bpk, lcT);
    gemm_kv_kernel<<<384, 256, 0, stream>>>(
        Apk, Bpk, wq_b, wk_b, wv_b, ph_re, ph_im, ampl, q, k, v, kvB);
    scan_kernel<<<256, 256, 0, stream>>>(kvB, lcT, ph_re, ph_im, ampl);
    chunk_out_kernel<<<BHTOT * NC, 512, 0, stream>>>(
        q, k, v, kvB, ph_re, ph_im, ampl, out);
}